// Round 6
// baseline (204.239 us; speedup 1.0000x reference)
//
#include <hip/hip_runtime.h>

// Problem constants
#define L_SEQ 2048
#define DIM   1024
#define NH    16
#define HDIM  64
#define KDIM  1024   // K for both GEMMs

typedef short  short8 __attribute__((ext_vector_type(8)));
typedef __bf16 bf16x8 __attribute__((ext_vector_type(8)));
typedef __bf16 bf16x4 __attribute__((ext_vector_type(4)));
typedef float  f32x4  __attribute__((ext_vector_type(4)));
typedef unsigned u32x4 __attribute__((ext_vector_type(4)));

__device__ __forceinline__ unsigned short f2bf(float f) {
  unsigned u = __builtin_bit_cast(unsigned, f);
  u += 0x7fffu + ((u >> 16) & 1u);   // RNE
  return (unsigned short)(u >> 16);
}

__device__ __forceinline__ void gload16(const void* g, void* l) {
  __builtin_amdgcn_global_load_lds(
      (const __attribute__((address_space(1))) void*)g,
      (__attribute__((address_space(3))) void*)l, 16, 0, 0);
}

__device__ __forceinline__ bf16x8 ldfrag(const unsigned short* p) {
  return __builtin_bit_cast(bf16x8, *(const short8*)p);
}
#define MFMA16(a, b, c) __builtin_amdgcn_mfma_f32_16x16x32_bf16(a, b, c, 0, 0, 0)

// pack two f32 -> one u32 of 2 bf16 (lo = a, hi = b)
__device__ __forceinline__ unsigned cvtpk(float a, float b) {
  unsigned r;
  asm("v_cvt_pk_bf16_f32 %0, %1, %2" : "=v"(r) : "v"(a), "v"(b));
  return r;
}
__device__ __forceinline__ void xchg(unsigned &a, unsigned &b) {
  asm("v_permlane32_swap_b32 %0, %1" : "+v"(a), "+v"(b));
  asm("v_permlane16_swap_b32 %0, %1" : "+v"(a), "+v"(b));
}

// ---------------- fp32 -> bf16 conversion ----------------
__global__ __launch_bounds__(256) void cvt_bf16(const float* __restrict__ src,
                                                unsigned short* __restrict__ dst,
                                                int n) {
  int i = (blockIdx.x * 256 + threadIdx.x) * 8;
  if (i >= n) return;
  f32x4 a = *(const f32x4*)(src + i);
  f32x4 b = *(const f32x4*)(src + i + 4);
  short8 o;
  o[0] = (short)f2bf(a[0]); o[1] = (short)f2bf(a[1]);
  o[2] = (short)f2bf(a[2]); o[3] = (short)f2bf(a[3]);
  o[4] = (short)f2bf(b[0]); o[5] = (short)f2bf(b[1]);
  o[6] = (short)f2bf(b[2]); o[7] = (short)f2bf(b[3]);
  *(short8*)(dst + i) = o;
}

// ---------------- zero-fill (graph-capture-safe memset) ----------------
__global__ __launch_bounds__(256) void zero_buf(f32x4* __restrict__ dst, int n4) {
  int i = blockIdx.x * 256 + threadIdx.x;
  if (i < n4) dst[i] = f32x4{0.f, 0.f, 0.f, 0.f};
}

// ---------------- mask prefix-scan: compacted key indices ----------------
__global__ __launch_bounds__(256) void mask_scan(const int* __restrict__ mask,
                                                 int* __restrict__ idx,
                                                 int* __restrict__ lc) {
  const int b = blockIdx.x, t = threadIdx.x;
  __shared__ int wsum[4];
  const int* mrow = mask + b * L_SEQ + t * 8;
  int m[8], c = 0;
#pragma unroll
  for (int i = 0; i < 8; ++i) { m[i] = mrow[i]; c += (m[i] == 0); }
  const int lane = t & 63, w = t >> 6;
  int sc = c;
#pragma unroll
  for (int d = 1; d < 64; d <<= 1) {
    int v = __shfl_up(sc, d);
    if (lane >= d) sc += v;
  }
  if (lane == 63) wsum[w] = sc;
  __syncthreads();
  int pre = sc - c;
  for (int i = 0; i < w; ++i) pre += wsum[i];
  int run = pre;
#pragma unroll
  for (int i = 0; i < 8; ++i) {
    idx[b * L_SEQ + t * 8 + i] = m[i] ? -1 : run;
    run += (m[i] == 0);
  }
  if (t == 255) lc[b] = run;
}

// ---------------- 256x128 NT GEMM mainloop, 4-phase counted-vmcnt pipeline ---
// A: [M,1024] rm bf16; Bt: [N,1024] rm bf16. 512 threads = 8 waves (2M x 4N).
// Per-wave C: 128 rows x 32 cols -> acc[8][2] f32x4.
// LDS tiles XOR-swizzled (T2): elem col ^= (row&7)<<3; gload dest linear,
// global source col pre-swizzled (both-sides rule).
// Schedule per K-tile T (buf = T&1):
//   q0: vmcnt(4); barrier; stage B(T+1)->buf^1; read A-lo,B-lo; MFMA lo*lo
//   q1: read B-hi; MFMA lo*hi
//   q2: read A-hi; MFMA hi*lo; barrier   (last reads of buf end here)
//   q3: stage A(T+2)->buf (freed); MFMA hi*hi
// vmcnt(4) = exactly the next tile's A-burst stays in flight (never 0 mid-loop).
__device__ __forceinline__ void gemm256_mainloop(
    const unsigned short* __restrict__ A, const unsigned short* __restrict__ Bt,
    int m0, int n0,
    unsigned short* As0, unsigned short* As1,
    unsigned short* Bs0, unsigned short* Bs1,
    f32x4 (&acc)[8][2]) {
  const int t = threadIdx.x;           // 512
  const int lane = t & 63, wid = t >> 6;
  const int wm = wid >> 2, wn = wid & 3;
  const int lr = lane & 15, lk = (lane >> 4) * 8;
  const int swr = (lr & 7) << 3;
  constexpr int NT = KDIM / 64;        // 16

  auto stageA = [&](unsigned short* dst, int kt, int h) {
#pragma unroll
    for (int i = 0; i < 2; ++i) {
      int c = i * 512 + t;             // 0..1023 within half
      int row = h * 128 + (c >> 3);
      int cs = ((c & 7) ^ (row & 7)) * 8;
      gload16(A + (size_t)(m0 + row) * KDIM + kt * 64 + cs,
              dst + row * 64 + (c & 7) * 8);
    }
  };
  auto stageB = [&](unsigned short* dst, int kt) {
#pragma unroll
    for (int i = 0; i < 2; ++i) {
      int c = i * 512 + t;             // 0..1023
      int row = c >> 3;
      int cs = ((c & 7) ^ (row & 7)) * 8;
      gload16(Bt + (size_t)(n0 + row) * KDIM + kt * 64 + cs,
              dst + row * 64 + (c & 7) * 8);
    }
  };

  // prologue: tile 0 fully (6 loads), A of tile 1 (4 loads)
  stageA(As0, 0, 0); stageA(As0, 0, 1); stageB(Bs0, 0);
  stageA(As1, 1, 0); stageA(As1, 1, 1);

  unsigned short *Ac = As0, *An = As1, *Bc = Bs0, *Bn = Bs1;

  for (int T = 0; T < NT; ++T) {
    if (T == NT - 1) { asm volatile("s_waitcnt vmcnt(0)" ::: "memory"); }
    else             { asm volatile("s_waitcnt vmcnt(4)" ::: "memory"); }
    __builtin_amdgcn_s_barrier();
    __builtin_amdgcn_sched_barrier(0);

    // ---- q0: stage B(T+1); read A-lo + B-lo; MFMA (mf0-3, nf0) ----
    if (T + 1 < NT) stageB(Bn, T + 1);
    bf16x8 a[4][2], a2[4][2], b0[2], b1[2];
#pragma unroll
    for (int mf = 0; mf < 4; ++mf)
#pragma unroll
      for (int kh = 0; kh < 2; ++kh)
        a[mf][kh] = ldfrag(Ac + (wm * 128 + mf * 16 + lr) * 64 +
                           ((kh * 32 + lk) ^ swr));
#pragma unroll
    for (int kh = 0; kh < 2; ++kh)
      b0[kh] = ldfrag(Bc + (wn * 32 + lr) * 64 + ((kh * 32 + lk) ^ swr));
    asm volatile("s_waitcnt lgkmcnt(0)" ::: "memory");
    __builtin_amdgcn_sched_barrier(0);
    __builtin_amdgcn_s_setprio(1);
#pragma unroll
    for (int mf = 0; mf < 4; ++mf) {
      acc[mf][0] = MFMA16(a[mf][0], b0[0], acc[mf][0]);
      acc[mf][0] = MFMA16(a[mf][1], b0[1], acc[mf][0]);
    }
    __builtin_amdgcn_s_setprio(0);
    __builtin_amdgcn_s_barrier();

    // ---- q1: read B-hi; MFMA (mf0-3, nf1) ----
#pragma unroll
    for (int kh = 0; kh < 2; ++kh)
      b1[kh] = ldfrag(Bc + (wn * 32 + 16 + lr) * 64 + ((kh * 32 + lk) ^ swr));
    asm volatile("s_waitcnt lgkmcnt(0)" ::: "memory");
    __builtin_amdgcn_sched_barrier(0);
    __builtin_amdgcn_s_setprio(1);
#pragma unroll
    for (int mf = 0; mf < 4; ++mf) {
      acc[mf][1] = MFMA16(a[mf][0], b1[0], acc[mf][1]);
      acc[mf][1] = MFMA16(a[mf][1], b1[1], acc[mf][1]);
    }
    __builtin_amdgcn_s_setprio(0);
    __builtin_amdgcn_s_barrier();

    // ---- q2: read A-hi; MFMA (mf4-7, nf0); barrier frees buf ----
#pragma unroll
    for (int mf = 0; mf < 4; ++mf)
#pragma unroll
      for (int kh = 0; kh < 2; ++kh)
        a2[mf][kh] = ldfrag(Ac + (wm * 128 + 64 + mf * 16 + lr) * 64 +
                            ((kh * 32 + lk) ^ swr));
    asm volatile("s_waitcnt lgkmcnt(0)" ::: "memory");
    __builtin_amdgcn_sched_barrier(0);
    __builtin_amdgcn_s_setprio(1);
#pragma unroll
    for (int mf = 0; mf < 4; ++mf) {
      acc[mf + 4][0] = MFMA16(a2[mf][0], b0[0], acc[mf + 4][0]);
      acc[mf + 4][0] = MFMA16(a2[mf][1], b0[1], acc[mf + 4][0]);
    }
    __builtin_amdgcn_s_setprio(0);
    __builtin_amdgcn_s_barrier();       // all reads of buf retired block-wide
    __builtin_amdgcn_sched_barrier(0);

    // ---- q3: stage A(T+2) into freed buf; MFMA (mf4-7, nf1) ----
    if (T + 2 < NT) { stageA(Ac, T + 2, 0); stageA(Ac, T + 2, 1); }
    __builtin_amdgcn_s_setprio(1);
#pragma unroll
    for (int mf = 0; mf < 4; ++mf) {
      acc[mf + 4][1] = MFMA16(a2[mf][0], b1[0], acc[mf + 4][1]);
      acc[mf + 4][1] = MFMA16(a2[mf][1], b1[1], acc[mf + 4][1]);
    }
    __builtin_amdgcn_s_setprio(0);

    unsigned short* tp;
    tp = Ac; Ac = An; An = tp;
    tp = Bc; Bc = Bn; Bn = tp;
  }
}

// ---------------- GEMM1: qkv = x @ Wqkv^T, scatter (K/V compacted) ----------
__global__ __launch_bounds__(512, 2) void gemm_qkv(
    const unsigned short* __restrict__ xb, const unsigned short* __restrict__ wb,
    const int* __restrict__ idx,
    unsigned short* __restrict__ qw, unsigned short* __restrict__ kw,
    unsigned short* __restrict__ vtw) {
  __shared__ unsigned short As[2][256 * 64];   // 64 KB
  __shared__ unsigned short Bs[2][128 * 64];   // 32 KB
  f32x4 acc[8][2] = {};
  const int n0 = blockIdx.x * 128, m0 = blockIdx.y * 256;
  gemm256_mainloop(xb, wb, m0, n0, As[0], As[1], Bs[0], Bs[1], acc);
  const int t = threadIdx.x, lane = t & 63, wid = t >> 6;
  const int wm = wid >> 2, wn = wid & 3;
  const int lr = lane & 15, g4 = ((lane >> 4) & 3) * 4;
  const int sec = n0 >> 10;              // 0=Q 1=K 2=V (block-uniform)
  const int nb = n0 & 1023;
  if (sec == 0) {
#pragma unroll
    for (int mf = 0; mf < 8; ++mf)
#pragma unroll
      for (int nf = 0; nf < 2; ++nf) {
        int e = nb + wn * 32 + nf * 16 + lr;
        int h = e >> 6, hd = e & 63;
#pragma unroll
        for (int r = 0; r < 4; ++r) {
          int m = m0 + wm * 128 + mf * 16 + g4 + r;
          int b = m >> 11, li = m & 2047;
          qw[(((size_t)(b * NH + h)) * L_SEQ + li) * HDIM + hd] =
              f2bf(acc[mf][nf][r]);
        }
      }
  } else {
#pragma unroll
    for (int mf = 0; mf < 8; ++mf)
#pragma unroll
      for (int r = 0; r < 4; ++r) {
        int m = m0 + wm * 128 + mf * 16 + g4 + r;
        int b = m >> 11, li = m & 2047;
        int tgt = idx[b * L_SEQ + li];   // -1 = PAD: drop row
        if (tgt < 0) continue;
        size_t bb = (size_t)b * NH;
#pragma unroll
        for (int nf = 0; nf < 2; ++nf) {
          int e = nb + wn * 32 + nf * 16 + lr;
          int h = e >> 6, hd = e & 63;
          unsigned short val = f2bf(acc[mf][nf][r]);
          if (sec == 1) kw[((bb + h) * L_SEQ + tgt) * HDIM + hd] = val;
          else          vtw[((bb + h) * HDIM + hd) * L_SEQ + tgt] = val;
        }
      }
  }
}

// ---------------- GEMM2: out = y @ Wproj^T (fp32 out) ----------------
__global__ __launch_bounds__(512, 2) void gemm_proj(
    const unsigned short* __restrict__ yb, const unsigned short* __restrict__ wb,
    float* __restrict__ out) {
  __shared__ unsigned short As[2][256 * 64];
  __shared__ unsigned short Bs[2][128 * 64];
  f32x4 acc[8][2] = {};
  const int n0 = blockIdx.x * 128, m0 = blockIdx.y * 256;
  gemm256_mainloop(yb, wb, m0, n0, As[0], As[1], Bs[0], Bs[1], acc);
  const int t = threadIdx.x, lane = t & 63, wid = t >> 6;
  const int wm = wid >> 2, wn = wid & 3;
  const int lr = lane & 15, g4 = ((lane >> 4) & 3) * 4;
#pragma unroll
  for (int mf = 0; mf < 8; ++mf)
#pragma unroll
    for (int nf = 0; nf < 2; ++nf) {
      int e = n0 + wn * 32 + nf * 16 + lr;
#pragma unroll
      for (int r = 0; r < 4; ++r) {
        int m = m0 + wm * 128 + mf * 16 + g4 + r;
        out[(size_t)m * DIM + e] = acc[mf][nf][r];
      }
    }
}

// ---------------- Flash attention over COMPACTED keys ----------------
__global__ __launch_bounds__(256, 4) void attn_kernel(
    const unsigned short* __restrict__ qw, const unsigned short* __restrict__ kw,
    const unsigned short* __restrict__ vtw, const int* __restrict__ lc,
    unsigned short* __restrict__ yb) {
  __shared__ unsigned short Ks[2][64 * 64];    // [buf][kv][hd] swizzled
  __shared__ unsigned short Vts[2][64 * 64];   // [buf][hd][kv] swizzled
  const int bh = blockIdx.y;
  const int q0 = blockIdx.x * 128;
  const int b = bh >> 4, h = bh & 15;
  const int t = threadIdx.x, wid = t >> 6, lane = t & 63;
  const int lr = lane & 15, lk = (lane >> 4) * 8, g4 = (lane >> 4) * 4;
  const int swr = (lr & 7) << 3;
  const float KE = 0.18033688011112042f;    // (1/sqrt(64)) * log2(e)

  const int Lcv = lc[b];
  const int nt = (Lcv + 63) >> 6;           // >=1 (never fully padded)

  bf16x8 qf[2][2];
  const size_t qbase = (size_t)bh * L_SEQ + q0 + wid * 32;
#pragma unroll
  for (int qi = 0; qi < 2; ++qi)
#pragma unroll
    for (int kh = 0; kh < 2; ++kh)
      qf[qi][kh] = __builtin_bit_cast(bf16x8,
          *(const short8*)(qw + (qbase + qi * 16 + lr) * HDIM + kh * 32 + lk));

  f32x4 o[2][4] = {};
  float mrun[2] = {-3.0e38f, -3.0e38f};
  float lrun[2] = {0.f, 0.f};

  auto stage = [&](int buf, int kt) {
#pragma unroll
    for (int i = 0; i < 2; ++i) {
      int c = i * 256 + t;
      int row = c >> 3;
      int cs = ((c & 7) ^ (row & 7)) * 8;
      gload16(kw  + ((size_t)bh * L_SEQ + kt * 64 + row) * HDIM + cs, &Ks[buf][c * 8]);
      gload16(vtw + ((size_t)bh * HDIM + row) * L_SEQ + kt * 64 + cs, &Vts[buf][c * 8]);
    }
  };

  stage(0, 0);
  int cur = 0;

  for (int kt = 0; kt < nt; ++kt) {
    if (kt + 1 < nt) {
      stage(cur ^ 1, kt + 1);
      asm volatile("s_waitcnt vmcnt(4)" ::: "memory");
    } else {
      asm volatile("s_waitcnt vmcnt(0)" ::: "memory");
    }
    __builtin_amdgcn_s_barrier();
    __builtin_amdgcn_sched_barrier(0);

    const unsigned short* Kc = Ks[cur];
    f32x4 s[2][4] = {};
    __builtin_amdgcn_s_setprio(1);
#pragma unroll
    for (int nf = 0; nf < 4; ++nf) {
      bf16x8 k0 = __builtin_bit_cast(bf16x8,
          *(const short8*)(Kc + (nf * 16 + lr) * 64 + ((0 + lk) ^ swr)));
      bf16x8 k1 = __builtin_bit_cast(bf16x8,
          *(const short8*)(Kc + (nf * 16 + lr) * 64 + ((32 + lk) ^ swr)));
      s[0][nf] = MFMA16(k0, qf[0][0], s[0][nf]);
      s[0][nf] = MFMA16(k1, qf[0][1], s[0][nf]);
      s[1][nf] = MFMA16(k0, qf[1][0], s[1][nf]);
      s[1][nf] = MFMA16(k1, qf[1][1], s[1][nf]);
    }
    __builtin_amdgcn_s_setprio(0);

    if (kt == nt - 1) {
      int kbase = kt * 64 + g4;
#pragma unroll
      for (int nf = 0; nf < 4; ++nf)
#pragma unroll
        for (int r = 0; r < 4; ++r)
          if (kbase + nf * 16 + r >= Lcv) {
            s[0][nf][r] = -3.0e38f;
            s[1][nf][r] = -3.0e38f;
          }
    }

    float pmax[2];
#pragma unroll
    for (int qi = 0; qi < 2; ++qi) {
      float a0 = fmaxf(fmaxf(s[qi][0][0], s[qi][0][1]), fmaxf(s[qi][0][2], s[qi][0][3]));
      float a1 = fmaxf(fmaxf(s[qi][1][0], s[qi][1][1]), fmaxf(s[qi][1][2], s[qi][1][3]));
      float a2 = fmaxf(fmaxf(s[qi][2][0], s[qi][2][1]), fmaxf(s[qi][2][2], s[qi][2][3]));
      float a3 = fmaxf(fmaxf(s[qi][3][0], s[qi][3][1]), fmaxf(s[qi][3][2], s[qi][3][3]));
      float mm = fmaxf(fmaxf(a0, a1), fmaxf(a2, a3));
      mm = fmaxf(mm, __shfl_xor(mm, 16));
      mm = fmaxf(mm, __shfl_xor(mm, 32));
      pmax[qi] = mm;
    }

    bool need = (pmax[0] > mrun[0] + 8.0f) || (pmax[1] > mrun[1] + 8.0f);
    if (__any(need)) {
#pragma unroll
      for (int qi = 0; qi < 2; ++qi) {
        float mn = fmaxf(mrun[qi], pmax[qi]);
        float al = __builtin_amdgcn_exp2f((mrun[qi] - mn) * KE);
        mrun[qi] = mn;
        lrun[qi] *= al;
#pragma unroll
        for (int df = 0; df < 4; ++df) o[qi][df] *= al;
      }
    }

    bf16x8 pb[2][2];
#pragma unroll
    for (int qi = 0; qi < 2; ++qi) {
      float mk_ = mrun[qi] * KE;
      f32x4 rs4 = {0.f, 0.f, 0.f, 0.f};
#pragma unroll
      for (int nf = 0; nf < 4; ++nf) {
#pragma unroll
        for (int r = 0; r < 4; ++r)
          s[qi][nf][r] = __builtin_amdgcn_exp2f(s[qi][nf][r] * KE - mk_);
        rs4 += s[qi][nf];
      }
      float rsum = (rs4[0] + rs4[1]) + (rs4[2] + rs4[3]);
      rsum += __shfl_xor(rsum, 16);
      rsum += __shfl_xor(rsum, 32);
      lrun[qi] += rsum;
      unsigned w00 = cvtpk(s[qi][0][0], s[qi][0][1]);
      unsigned w01 = cvtpk(s[qi][0][2], s[qi][0][3]);
      unsigned w10 = cvtpk(s[qi][1][0], s[qi][1][1]);
      unsigned w11 = cvtpk(s[qi][1][2], s[qi][1][3]);
      unsigned w20 = cvtpk(s[qi][2][0], s[qi][2][1]);
      unsigned w21 = cvtpk(s[qi][2][2], s[qi][2][3]);
      unsigned w30 = cvtpk(s[qi][3][0], s[qi][3][1]);
      unsigned w31 = cvtpk(s[qi][3][2], s[qi][3][3]);
      xchg(w00, w10);
      xchg(w01, w11);
      xchg(w20, w30);
      xchg(w21, w31);
      u32x4 f0 = {w00, w01, w10, w11};
      u32x4 f1 = {w20, w21, w30, w31};
      pb[qi][0] = __builtin_bit_cast(bf16x8, f0);
      pb[qi][1] = __builtin_bit_cast(bf16x8, f1);
    }

    const unsigned short* Vc = Vts[cur];
    __builtin_amdgcn_s_setprio(1);
#pragma unroll
    for (int df = 0; df < 4; ++df) {
      bf16x8 v0 = __builtin_bit_cast(bf16x8,
          *(const short8*)(Vc + (df * 16 + lr) * 64 + ((0 + lk) ^ swr)));
      bf16x8 v1 = __builtin_bit_cast(bf16x8,
          *(const short8*)(Vc + (df * 16 + lr) * 64 + ((32 + lk) ^ swr)));
      o[0][df] = MFMA16(v0, pb[0][0], o[0][df]);
      o[0][df] = MFMA16(v1, pb[0][1], o[0][df]);
      o[1][df] = MFMA16(v0, pb[1][0], o[1][df]);
      o[1][df] = MFMA16(v1, pb[1][1], o[1][df]);
    }
    __builtin_amdgcn_s_setprio(0);

    __builtin_amdgcn_sched_barrier(0);
    __builtin_amdgcn_s_barrier();
    cur ^= 1;
  }

#pragma unroll
  for (int qi = 0; qi < 2; ++qi) {
    float inv = 1.0f / lrun[qi];
    int q = q0 + wid * 32 + qi * 16 + lr;
#pragma unroll
    for (int df = 0; df < 4; ++df) {
      bf16x4 pk = {(__bf16)(o[qi][df][0] * inv), (__bf16)(o[qi][df][1] * inv),
                   (__bf16)(o[qi][df][2] * inv), (__bf16)(o[qi][df][3] * inv)};
      *(bf16x4*)(yb + ((size_t)b * L_SEQ + q) * DIM + h * 64 + df * 16 + g4) = pk;
    }
  }
}

// ---------------- launch ----------------
extern "C" void kernel_launch(void* const* d_in, const int* in_sizes, int n_in,
                              void* d_out, int out_size, void* d_ws, size_t ws_size,
                              hipStream_t stream) {
  const float* x     = (const float*)d_in[0];
  const int*   mask  = (const int*)d_in[1];
  const float* wqkv  = (const float*)d_in[2];
  const float* wproj = (const float*)d_in[3];
  char* ws = (char*)d_ws;
  unsigned short* xb     = (unsigned short*)(ws + 0);          // 16 MiB
  unsigned short* wqkvb  = (unsigned short*)(ws + 16777216);   // 6 MiB
  unsigned short* wprojb = (unsigned short*)(ws + 23068672);   // 2 MiB
  unsigned short* qw     = (unsigned short*)(ws + 25165824);   // 16 MiB
  unsigned short* kw     = (unsigned short*)(ws + 41943040);   // 16 MiB
  unsigned short* vtw    = (unsigned short*)(ws + 58720256);   // 16 MiB
  unsigned short* yb     = (unsigned short*)(ws + 75497472);   // 16 MiB
  int*            idx    = (int*)(ws + 92274688);              // 32 KiB
  int*            lcArr  = (int*)(ws + 92307456);              // 16 B

  cvt_bf16<<<dim3(8388608 / 2048), 256, 0, stream>>>(x, xb, 8388608);
  cvt_bf16<<<dim3(3145728 / 2048), 256, 0, stream>>>(wqkv, wqkvb, 3145728);
  cvt_bf16<<<dim3(1048576 / 2048), 256, 0, stream>>>(wproj, wprojb, 1048576);
  mask_scan<<<dim3(4), 256, 0, stream>>>(mask, idx, lcArr);
  zero_buf<<<dim3(4096), 256, 0, stream>>>((f32x4*)vtw, 1048576);  // V tail NaN-safe
  gemm_qkv<<<dim3(24, 32), 512, 0, stream>>>(xb, wqkvb, idx, qw, kw, vtw);
  attn_kernel<<<dim3(16, 64), 256, 0, stream>>>(qw, kw, vtw, lcArr, yb);
  gemm_proj<<<dim3(8, 32), 512, 0, stream>>>(yb, wprojb, (float*)d_out);
}

// Round 7
// 193.872 us; speedup vs baseline: 1.0535x; 1.0535x over previous
//
#include <hip/hip_runtime.h>

// Problem constants
#define L_SEQ 2048
#define DIM   1024
#define NH    16
#define HDIM  64
#define KDIM  1024   // K for both GEMMs

typedef short  short8 __attribute__((ext_vector_type(8)));
typedef __bf16 bf16x8 __attribute__((ext_vector_type(8)));
typedef __bf16 bf16x4 __attribute__((ext_vector_type(4)));
typedef float  f32x4  __attribute__((ext_vector_type(4)));
typedef unsigned u32x4 __attribute__((ext_vector_type(4)));

__device__ __forceinline__ unsigned short f2bf(float f) {
  unsigned u = __builtin_bit_cast(unsigned, f);
  u += 0x7fffu + ((u >> 16) & 1u);   // RNE
  return (unsigned short)(u >> 16);
}

__device__ __forceinline__ void gload16(const void* g, void* l) {
  __builtin_amdgcn_global_load_lds(
      (const __attribute__((address_space(1))) void*)g,
      (__attribute__((address_space(3))) void*)l, 16, 0, 0);
}

__device__ __forceinline__ bf16x8 ldfrag(const unsigned short* p) {
  return __builtin_bit_cast(bf16x8, *(const short8*)p);
}
#define MFMA16(a, b, c) __builtin_amdgcn_mfma_f32_16x16x32_bf16(a, b, c, 0, 0, 0)

// pack two f32 -> one u32 of 2 bf16 (lo = a, hi = b)
__device__ __forceinline__ unsigned cvtpk(float a, float b) {
  unsigned r;
  asm("v_cvt_pk_bf16_f32 %0, %1, %2" : "=v"(r) : "v"(a), "v"(b));
  return r;
}
__device__ __forceinline__ void xchg(unsigned &a, unsigned &b) {
  asm("v_permlane32_swap_b32 %0, %1" : "+v"(a), "+v"(b));
  asm("v_permlane16_swap_b32 %0, %1" : "+v"(a), "+v"(b));
}

// ---------------- fp32 -> bf16 conversion ----------------
__global__ __launch_bounds__(256) void cvt_bf16(const float* __restrict__ src,
                                                unsigned short* __restrict__ dst,
                                                int n) {
  int i = (blockIdx.x * 256 + threadIdx.x) * 8;
  if (i >= n) return;
  f32x4 a = *(const f32x4*)(src + i);
  f32x4 b = *(const f32x4*)(src + i + 4);
  short8 o;
  o[0] = (short)f2bf(a[0]); o[1] = (short)f2bf(a[1]);
  o[2] = (short)f2bf(a[2]); o[3] = (short)f2bf(a[3]);
  o[4] = (short)f2bf(b[0]); o[5] = (short)f2bf(b[1]);
  o[6] = (short)f2bf(b[2]); o[7] = (short)f2bf(b[3]);
  *(short8*)(dst + i) = o;
}

// ---------------- zero-fill (graph-capture-safe memset) ----------------
__global__ __launch_bounds__(256) void zero_buf(f32x4* __restrict__ dst, int n4) {
  int i = blockIdx.x * 256 + threadIdx.x;
  if (i < n4) dst[i] = f32x4{0.f, 0.f, 0.f, 0.f};
}

// ---------------- mask prefix-scan: compacted key indices ----------------
__global__ __launch_bounds__(256) void mask_scan(const int* __restrict__ mask,
                                                 int* __restrict__ idx,
                                                 int* __restrict__ lc) {
  const int b = blockIdx.x, t = threadIdx.x;
  __shared__ int wsum[4];
  const int* mrow = mask + b * L_SEQ + t * 8;
  int m[8], c = 0;
#pragma unroll
  for (int i = 0; i < 8; ++i) { m[i] = mrow[i]; c += (m[i] == 0); }
  const int lane = t & 63, w = t >> 6;
  int sc = c;
#pragma unroll
  for (int d = 1; d < 64; d <<= 1) {
    int v = __shfl_up(sc, d);
    if (lane >= d) sc += v;
  }
  if (lane == 63) wsum[w] = sc;
  __syncthreads();
  int pre = sc - c;
  for (int i = 0; i < w; ++i) pre += wsum[i];
  int run = pre;
#pragma unroll
  for (int i = 0; i < 8; ++i) {
    idx[b * L_SEQ + t * 8 + i] = m[i] ? -1 : run;
    run += (m[i] == 0);
  }
  if (t == 255) lc[b] = run;
}

// ---------------- 256x256 NT GEMM mainloop — m201 8-phase template ----------
// A: [M,1024] rm bf16; Bt: [N,1024] rm bf16. 512 threads = 8 waves (2M x 4N).
// Wave output 128x64 -> acc[8][4]. LDS: A dbuf 2x[256][64], B dbuf 2x[256][64]
// (128 KiB), XOR-swizzled (elem col ^= (row&7)<<3); gload dest linear, global
// source col inverse-swizzled.
// Iter i = K-tiles 2i (buf0, phases 1-4) and 2i+1 (buf1, phases 5-8).
// Phase s of a tile: read A-stripe s (4 ds_read; +B all 8 at s=0), issue ONE
// half-tile stage, [vmcnt(4) at ph4/ph8], barrier, lgkm(0), 16 MFMA, barrier.
// Stage slots: ph1,2=A(2i+1)->As1; ph3,4=B(2i+2)->Bs0; ph5,6=A(2i+2)->As0;
// ph7,8=B(2i+3)->Bs1. Each destination's last reader is >=1 barrier earlier.
// vmcnt(4): the 2 stages just issued (4 loads) may stay in flight; everything
// older (the data the NEXT phase group reads) has landed.
__device__ __forceinline__ void gemm256_mainloop(
    const unsigned short* __restrict__ A, const unsigned short* __restrict__ Bt,
    int m0, int n0,
    unsigned short* As0, unsigned short* As1,
    unsigned short* Bs0, unsigned short* Bs1,
    f32x4 (&acc)[8][4]) {
  const int t = threadIdx.x;           // 512
  const int lane = t & 63, wid = t >> 6;
  const int wm = wid >> 2, wn = wid & 3;
  const int lr = lane & 15, lk = (lane >> 4) * 8;
  const int swr = (lr & 7) << 3;
  constexpr int NT = KDIM / 64;        // 16
  constexpr int NI = NT / 2;           // 8

  auto stA = [&](unsigned short* dst, int kt, int h) {
#pragma unroll
    for (int i = 0; i < 2; ++i) {
      int c = i * 512 + t;             // 0..1023 within half
      int row = h * 128 + (c >> 3);
      int cs = ((c & 7) ^ (row & 7)) * 8;
      gload16(A + (size_t)(m0 + row) * KDIM + kt * 64 + cs,
              dst + row * 64 + (c & 7) * 8);
    }
  };
  auto stB = [&](unsigned short* dst, int kt, int h) {
#pragma unroll
    for (int i = 0; i < 2; ++i) {
      int c = i * 512 + t;
      int row = h * 128 + (c >> 3);
      int cs = ((c & 7) ^ (row & 7)) * 8;
      gload16(Bt + (size_t)(n0 + row) * KDIM + kt * 64 + cs,
              dst + row * 64 + (c & 7) * 8);
    }
  };

  // prologue: A(0), B(0) fully; B(1) fully. A(1) staged at iter0 ph1,2.
  stA(As0, 0, 0); stA(As0, 0, 1);
  stB(Bs0, 0, 0); stB(Bs0, 0, 1);
  stB(Bs1, 1, 0); stB(Bs1, 1, 1);
  asm volatile("s_waitcnt vmcnt(4)" ::: "memory");   // A(0),B(0) landed
  __builtin_amdgcn_s_barrier();

  for (int i = 0; i < NI; ++i) {
    const bool more = (i + 1 < NI);
#pragma unroll
    for (int halfi = 0; halfi < 2; ++halfi) {
      const unsigned short* Ab = halfi ? As1 : As0;
      const unsigned short* Bb = halfi ? Bs1 : Bs0;
      bf16x8 bn[4][2];
#pragma unroll
      for (int s = 0; s < 4; ++s) {
        // ---- ds_reads for THIS phase's MFMA ----
        if (s == 0) {
#pragma unroll
          for (int nf = 0; nf < 4; ++nf)
#pragma unroll
            for (int kh = 0; kh < 2; ++kh)
              bn[nf][kh] = ldfrag(Bb + (wn * 64 + nf * 16 + lr) * 64 +
                                  ((kh * 32 + lk) ^ swr));
        }
        bf16x8 a[2][2];
#pragma unroll
        for (int mf2 = 0; mf2 < 2; ++mf2)
#pragma unroll
          for (int kh = 0; kh < 2; ++kh)
            a[mf2][kh] = ldfrag(Ab + (wm * 128 + s * 32 + mf2 * 16 + lr) * 64 +
                                ((kh * 32 + lk) ^ swr));
        // ---- one half-tile stage per phase ----
        if (halfi == 0) {
          if (s == 0)      stA(As1, 2 * i + 1, 0);
          else if (s == 1) stA(As1, 2 * i + 1, 1);
          else if (s == 2) { if (more) stB(Bs0, 2 * i + 2, 0); }
          else {
            if (more) { stB(Bs0, 2 * i + 2, 1);
                        asm volatile("s_waitcnt vmcnt(4)" ::: "memory"); }
            else      { asm volatile("s_waitcnt vmcnt(0)" ::: "memory"); }
          }
        } else {
          if (s == 0)      { if (more) stA(As0, 2 * i + 2, 0); }
          else if (s == 1) { if (more) stA(As0, 2 * i + 2, 1); }
          else if (s == 2) { if (more) stB(Bs1, 2 * i + 3, 0); }
          else {
            if (more) { stB(Bs1, 2 * i + 3, 1);
                        asm volatile("s_waitcnt vmcnt(4)" ::: "memory"); }
            else      { asm volatile("s_waitcnt vmcnt(0)" ::: "memory"); }
          }
        }
        __builtin_amdgcn_sched_barrier(0);
        __builtin_amdgcn_s_barrier();
        asm volatile("s_waitcnt lgkmcnt(0)" ::: "memory");
        __builtin_amdgcn_sched_barrier(0);
        __builtin_amdgcn_s_setprio(1);
#pragma unroll
        for (int mf2 = 0; mf2 < 2; ++mf2)
#pragma unroll
          for (int nf = 0; nf < 4; ++nf) {
            acc[s * 2 + mf2][nf] = MFMA16(a[mf2][0], bn[nf][0], acc[s * 2 + mf2][nf]);
            acc[s * 2 + mf2][nf] = MFMA16(a[mf2][1], bn[nf][1], acc[s * 2 + mf2][nf]);
          }
        __builtin_amdgcn_s_setprio(0);
        __builtin_amdgcn_s_barrier();
      }
    }
  }
}

// ---------------- GEMM1: qkv = x @ Wqkv^T, scatter (K/V compacted) ----------
__global__ __launch_bounds__(512, 2) void gemm_qkv(
    const unsigned short* __restrict__ xb, const unsigned short* __restrict__ wb,
    const int* __restrict__ idx,
    unsigned short* __restrict__ qw, unsigned short* __restrict__ kw,
    unsigned short* __restrict__ vtw) {
  __shared__ unsigned short As[2][256 * 64];   // 64 KB
  __shared__ unsigned short Bs[2][256 * 64];   // 64 KB
  f32x4 acc[8][4] = {};
  const int n0 = blockIdx.x * 256, m0 = blockIdx.y * 256;
  gemm256_mainloop(xb, wb, m0, n0, As[0], As[1], Bs[0], Bs[1], acc);
  const int t = threadIdx.x, lane = t & 63, wid = t >> 6;
  const int wm = wid >> 2, wn = wid & 3;
  const int lr = lane & 15, g4 = (lane >> 4) * 4;
  const int sec = n0 >> 10;              // 0=Q 1=K 2=V (block-uniform, 1024%256==0)
  const int nb = n0 & 1023;
  if (sec == 0) {
#pragma unroll
    for (int mf = 0; mf < 8; ++mf)
#pragma unroll
      for (int nf = 0; nf < 4; ++nf) {
        int e = nb + wn * 64 + nf * 16 + lr;
        int h = e >> 6, hd = e & 63;
#pragma unroll
        for (int r = 0; r < 4; ++r) {
          int m = m0 + wm * 128 + mf * 16 + g4 + r;
          int b = m >> 11, li = m & 2047;
          qw[(((size_t)(b * NH + h)) * L_SEQ + li) * HDIM + hd] =
              f2bf(acc[mf][nf][r]);
        }
      }
  } else {
#pragma unroll
    for (int mf = 0; mf < 8; ++mf)
#pragma unroll
      for (int r = 0; r < 4; ++r) {
        int m = m0 + wm * 128 + mf * 16 + g4 + r;
        int b = m >> 11, li = m & 2047;
        int tgt = idx[b * L_SEQ + li];   // -1 = PAD: drop row
        if (tgt < 0) continue;
        size_t bb = (size_t)b * NH;
#pragma unroll
        for (int nf = 0; nf < 4; ++nf) {
          int e = nb + wn * 64 + nf * 16 + lr;
          int h = e >> 6, hd = e & 63;
          unsigned short val = f2bf(acc[mf][nf][r]);
          if (sec == 1) kw[((bb + h) * L_SEQ + tgt) * HDIM + hd] = val;
          else          vtw[((bb + h) * HDIM + hd) * L_SEQ + tgt] = val;
        }
      }
  }
}

// ---------------- GEMM2: out = y @ Wproj^T (fp32 out) ----------------
__global__ __launch_bounds__(512, 2) void gemm_proj(
    const unsigned short* __restrict__ yb, const unsigned short* __restrict__ wb,
    float* __restrict__ out) {
  __shared__ unsigned short As[2][256 * 64];
  __shared__ unsigned short Bs[2][256 * 64];
  f32x4 acc[8][4] = {};
  const int n0 = blockIdx.x * 256, m0 = blockIdx.y * 256;
  gemm256_mainloop(yb, wb, m0, n0, As[0], As[1], Bs[0], Bs[1], acc);
  const int t = threadIdx.x, lane = t & 63, wid = t >> 6;
  const int wm = wid >> 2, wn = wid & 3;
  const int lr = lane & 15, g4 = (lane >> 4) * 4;
#pragma unroll
  for (int mf = 0; mf < 8; ++mf)
#pragma unroll
    for (int nf = 0; nf < 4; ++nf) {
      int e = n0 + wn * 64 + nf * 16 + lr;
#pragma unroll
      for (int r = 0; r < 4; ++r) {
        int m = m0 + wm * 128 + mf * 16 + g4 + r;
        out[(size_t)m * DIM + e] = acc[mf][nf][r];
      }
    }
}

// ---------------- Flash attention over COMPACTED keys ----------------
__global__ __launch_bounds__(256, 4) void attn_kernel(
    const unsigned short* __restrict__ qw, const unsigned short* __restrict__ kw,
    const unsigned short* __restrict__ vtw, const int* __restrict__ lc,
    unsigned short* __restrict__ yb) {
  __shared__ unsigned short Ks[2][64 * 64];    // [buf][kv][hd] swizzled
  __shared__ unsigned short Vts[2][64 * 64];   // [buf][hd][kv] swizzled
  const int bh = blockIdx.y;
  const int q0 = blockIdx.x * 128;
  const int b = bh >> 4, h = bh & 15;
  const int t = threadIdx.x, wid = t >> 6, lane = t & 63;
  const int lr = lane & 15, lk = (lane >> 4) * 8, g4 = (lane >> 4) * 4;
  const int swr = (lr & 7) << 3;
  const float KE = 0.18033688011112042f;    // (1/sqrt(64)) * log2(e)

  const int Lcv = lc[b];
  const int nt = (Lcv + 63) >> 6;           // >=1 (never fully padded)

  bf16x8 qf[2][2];
  const size_t qbase = (size_t)bh * L_SEQ + q0 + wid * 32;
#pragma unroll
  for (int qi = 0; qi < 2; ++qi)
#pragma unroll
    for (int kh = 0; kh < 2; ++kh)
      qf[qi][kh] = __builtin_bit_cast(bf16x8,
          *(const short8*)(qw + (qbase + qi * 16 + lr) * HDIM + kh * 32 + lk));

  f32x4 o[2][4] = {};
  float mrun[2] = {-3.0e38f, -3.0e38f};
  float lrun[2] = {0.f, 0.f};

  auto stage = [&](int buf, int kt) {
#pragma unroll
    for (int i = 0; i < 2; ++i) {
      int c = i * 256 + t;
      int row = c >> 3;
      int cs = ((c & 7) ^ (row & 7)) * 8;
      gload16(kw  + ((size_t)bh * L_SEQ + kt * 64 + row) * HDIM + cs, &Ks[buf][c * 8]);
      gload16(vtw + ((size_t)bh * HDIM + row) * L_SEQ + kt * 64 + cs, &Vts[buf][c * 8]);
    }
  };

  stage(0, 0);
  int cur = 0;

  for (int kt = 0; kt < nt; ++kt) {
    if (kt + 1 < nt) {
      stage(cur ^ 1, kt + 1);
      asm volatile("s_waitcnt vmcnt(4)" ::: "memory");
    } else {
      asm volatile("s_waitcnt vmcnt(0)" ::: "memory");
    }
    __builtin_amdgcn_s_barrier();
    __builtin_amdgcn_sched_barrier(0);

    const unsigned short* Kc = Ks[cur];
    f32x4 s[2][4] = {};
    __builtin_amdgcn_s_setprio(1);
#pragma unroll
    for (int nf = 0; nf < 4; ++nf) {
      bf16x8 k0 = __builtin_bit_cast(bf16x8,
          *(const short8*)(Kc + (nf * 16 + lr) * 64 + ((0 + lk) ^ swr)));
      bf16x8 k1 = __builtin_bit_cast(bf16x8,
          *(const short8*)(Kc + (nf * 16 + lr) * 64 + ((32 + lk) ^ swr)));
      s[0][nf] = MFMA16(k0, qf[0][0], s[0][nf]);
      s[0][nf] = MFMA16(k1, qf[0][1], s[0][nf]);
      s[1][nf] = MFMA16(k0, qf[1][0], s[1][nf]);
      s[1][nf] = MFMA16(k1, qf[1][1], s[1][nf]);
    }
    __builtin_amdgcn_s_setprio(0);

    if (kt == nt - 1) {
      int kbase = kt * 64 + g4;
#pragma unroll
      for (int nf = 0; nf < 4; ++nf)
#pragma unroll
        for (int r = 0; r < 4; ++r)
          if (kbase + nf * 16 + r >= Lcv) {
            s[0][nf][r] = -3.0e38f;
            s[1][nf][r] = -3.0e38f;
          }
    }

    float pmax[2];
#pragma unroll
    for (int qi = 0; qi < 2; ++qi) {
      float a0 = fmaxf(fmaxf(s[qi][0][0], s[qi][0][1]), fmaxf(s[qi][0][2], s[qi][0][3]));
      float a1 = fmaxf(fmaxf(s[qi][1][0], s[qi][1][1]), fmaxf(s[qi][1][2], s[qi][1][3]));
      float a2 = fmaxf(fmaxf(s[qi][2][0], s[qi][2][1]), fmaxf(s[qi][2][2], s[qi][2][3]));
      float a3 = fmaxf(fmaxf(s[qi][3][0], s[qi][3][1]), fmaxf(s[qi][3][2], s[qi][3][3]));
      float mm = fmaxf(fmaxf(a0, a1), fmaxf(a2, a3));
      mm = fmaxf(mm, __shfl_xor(mm, 16));
      mm = fmaxf(mm, __shfl_xor(mm, 32));
      pmax[qi] = mm;
    }

    bool need = (pmax[0] > mrun[0] + 8.0f) || (pmax[1] > mrun[1] + 8.0f);
    if (__any(need)) {
#pragma unroll
      for (int qi = 0; qi < 2; ++qi) {
        float mn = fmaxf(mrun[qi], pmax[qi]);
        float al = __builtin_amdgcn_exp2f((mrun[qi] - mn) * KE);
        mrun[qi] = mn;
        lrun[qi] *= al;
#pragma unroll
        for (int df = 0; df < 4; ++df) o[qi][df] *= al;
      }
    }

    bf16x8 pb[2][2];
#pragma unroll
    for (int qi = 0; qi < 2; ++qi) {
      float mk_ = mrun[qi] * KE;
      f32x4 rs4 = {0.f, 0.f, 0.f, 0.f};
#pragma unroll
      for (int nf = 0; nf < 4; ++nf) {
#pragma unroll
        for (int r = 0; r < 4; ++r)
          s[qi][nf][r] = __builtin_amdgcn_exp2f(s[qi][nf][r] * KE - mk_);
        rs4 += s[qi][nf];
      }
      float rsum = (rs4[0] + rs4[1]) + (rs4[2] + rs4[3]);
      rsum += __shfl_xor(rsum, 16);
      rsum += __shfl_xor(rsum, 32);
      lrun[qi] += rsum;
      unsigned w00 = cvtpk(s[qi][0][0], s[qi][0][1]);
      unsigned w01 = cvtpk(s[qi][0][2], s[qi][0][3]);
      unsigned w10 = cvtpk(s[qi][1][0], s[qi][1][1]);
      unsigned w11 = cvtpk(s[qi][1][2], s[qi][1][3]);
      unsigned w20 = cvtpk(s[qi][2][0], s[qi][2][1]);
      unsigned w21 = cvtpk(s[qi][2][2], s[qi][2][3]);
      unsigned w30 = cvtpk(s[qi][3][0], s[qi][3][1]);
      unsigned w31 = cvtpk(s[qi][3][2], s[qi][3][3]);
      xchg(w00, w10);
      xchg(w01, w11);
      xchg(w20, w30);
      xchg(w21, w31);
      u32x4 f0 = {w00, w01, w10, w11};
      u32x4 f1 = {w20, w21, w30, w31};
      pb[qi][0] = __builtin_bit_cast(bf16x8, f0);
      pb[qi][1] = __builtin_bit_cast(bf16x8, f1);
    }

    const unsigned short* Vc = Vts[cur];
    __builtin_amdgcn_s_setprio(1);
#pragma unroll
    for (int df = 0; df < 4; ++df) {
      bf16x8 v0 = __builtin_bit_cast(bf16x8,
          *(const short8*)(Vc + (df * 16 + lr) * 64 + ((0 + lk) ^ swr)));
      bf16x8 v1 = __builtin_bit_cast(bf16x8,
          *(const short8*)(Vc + (df * 16 + lr) * 64 + ((32 + lk) ^ swr)));
      o[0][df] = MFMA16(v0, pb[0][0], o[0][df]);
      o[0][df] = MFMA16(v1, pb[0][1], o[0][df]);
      o[1][df] = MFMA16(v0, pb[1][0], o[1][df]);
      o[1][df] = MFMA16(v1, pb[1][1], o[1][df]);
    }
    __builtin_amdgcn_s_setprio(0);

    __builtin_amdgcn_sched_barrier(0);
    __builtin_amdgcn_s_barrier();
    cur ^= 1;
  }

#pragma unroll
  for (int qi = 0; qi < 2; ++qi) {
    float inv = 1.0f / lrun[qi];
    int q = q0 + wid * 32 + qi * 16 + lr;
#pragma unroll
    for (int df = 0; df < 4; ++df) {
      bf16x4 pk = {(__bf16)(o[qi][df][0] * inv), (__bf16)(o[qi][df][1] * inv),
                   (__bf16)(o[qi][df][2] * inv), (__bf16)(o[qi][df][3] * inv)};
      *(bf16x4*)(yb + ((size_t)b * L_SEQ + q) * DIM + h * 64 + df * 16 + g4) = pk;
    }
  }
}

// ---------------- launch ----------------
extern "C" void kernel_launch(void* const* d_in, const int* in_sizes, int n_in,
                              void* d_out, int out_size, void* d_ws, size_t ws_size,
                              hipStream_t stream) {
  const float* x     = (const float*)d_in[0];
  const int*   mask  = (const int*)d_in[1];
  const float* wqkv  = (const float*)d_in[2];
  const float* wproj = (const float*)d_in[3];
  char* ws = (char*)d_ws;
  unsigned short* xb     = (unsigned short*)(ws + 0);          // 16 MiB
  unsigned short* wqkvb  = (unsigned short*)(ws + 16777216);   // 6 MiB
  unsigned short* wprojb = (unsigned short*)(ws + 23068672);   // 2 MiB
  unsigned short* qw     = (unsigned short*)(ws + 25165824);   // 16 MiB
  unsigned short* kw     = (unsigned short*)(ws + 41943040);   // 16 MiB
  unsigned short* vtw    = (unsigned short*)(ws + 58720256);   // 16 MiB
  unsigned short* yb     = (unsigned short*)(ws + 75497472);   // 16 MiB
  int*            idx    = (int*)(ws + 92274688);              // 32 KiB
  int*            lcArr  = (int*)(ws + 92307456);              // 16 B

  cvt_bf16<<<dim3(8388608 / 2048), 256, 0, stream>>>(x, xb, 8388608);
  cvt_bf16<<<dim3(3145728 / 2048), 256, 0, stream>>>(wqkv, wqkvb, 3145728);
  cvt_bf16<<<dim3(1048576 / 2048), 256, 0, stream>>>(wproj, wprojb, 1048576);
  mask_scan<<<dim3(4), 256, 0, stream>>>(mask, idx, lcArr);
  zero_buf<<<dim3(4096), 256, 0, stream>>>((f32x4*)vtw, 1048576);  // V tail NaN-safe
  gemm_qkv<<<dim3(12, 32), 512, 0, stream>>>(xb, wqkvb, idx, qw, kw, vtw);
  attn_kernel<<<dim3(16, 64), 256, 0, stream>>>(qw, kw, vtw, lcArr, yb);
  gemm_proj<<<dim3(4, 32), 512, 0, stream>>>(yb, wprojb, (float*)d_out);
}